// Round 1
// baseline (1064.603 us; speedup 1.0000x reference)
//
#include <hip/hip_runtime.h>

// Problem: per-edge MLP  out = relu(relu([h[src],h[dst]] @ W1.T + b1) @ W2.T + b2) @ W3.T + b3
// N=100000 nodes, H=128, E=1.6M edges, layers 256->64->32->6, all fp32.
//
// Strategy: layer 1 is linear over the concat, so precompute per-node
//   pre[n][j]    = sum_k h[n][k] * W1[j][k]       + b1[j]   (j<64, "src half", b1 folded)
//   pre[n][64+j] = sum_k h[n][k] * W1[j][128+k]             ("dst half")
// Then per edge: y[j] = pre[src][j] + pre[dst][64+j]; relu; 64->32->6 dense in registers.
// Cuts FLOPs 59.6G -> ~10.7G (no fp32 MFMA on CDNA4, so FLOP count is the ceiling).

#define H 128

// ---------------- weight prep: transposes so inner loops read contiguous, ----
// ---------------- wave-uniform rows (compiler -> s_load scalar broadcasts) ---
__global__ void prep_weights(const float* __restrict__ W1,
                             const float* __restrict__ W2,
                             const float* __restrict__ W3,
                             float* __restrict__ Wct,   // [128][128]: Wct[k][j] = concat-W1 column
                             float* __restrict__ W2t,   // [64][32]:  W2t[k][j] = W2[j][k]
                             float* __restrict__ W3t)   // [32][6]:   W3t[k][j] = W3[j][k]
{
    int t = blockIdx.x * blockDim.x + threadIdx.x;
    int stride = gridDim.x * blockDim.x;
    // Wct[k*128+j]: j<64 -> W1[j][k] ; j>=64 -> W1[j-64][128+k]
    for (int i = t; i < 128 * 128; i += stride) {
        int k = i >> 7, j = i & 127;
        Wct[i] = (j < 64) ? W1[j * 256 + k] : W1[(j - 64) * 256 + 128 + k];
    }
    for (int i = t; i < 64 * 32; i += stride) {
        int k = i >> 5, j = i & 31;
        W2t[i] = W2[j * 64 + k];
    }
    for (int i = t; i < 32 * 6; i += stride) {
        int k = i / 6, j = i - k * 6;
        W3t[i] = W3[j * 32 + k];
    }
}

// ---------------- per-node precompute: pre = h @ Wct (+ b1 on first half) ----
// Block = 256 threads = 2 nodes/iter (j = tid&127 selects output column).
// Each thread pins its Wct column in 128 VGPRs; h[n][k] is wave-uniform -> s_load.
__global__ void node_precompute(const float* __restrict__ h,
                                const float* __restrict__ Wct,
                                const float* __restrict__ b1,
                                float* __restrict__ pre, int N)
{
    const int j = threadIdx.x & 127;
    const int half = threadIdx.x >> 7;   // wave-uniform (waves 0,1 -> 0; waves 2,3 -> 1)
    float w[H];
#pragma unroll
    for (int k = 0; k < H; k++) w[k] = Wct[k * 128 + j];
    const float bj = (j < 64) ? b1[j] : 0.f;

    for (int n = blockIdx.x * 2 + half; n < N; n += gridDim.x * 2) {
        const float* hn = h + (size_t)n * H;
        float a0 = 0.f, a1 = 0.f, a2 = 0.f, a3 = 0.f;   // 4 chains for FMA-latency ILP
#pragma unroll
        for (int k = 0; k < H; k += 4) {
            a0 = fmaf(hn[k + 0], w[k + 0], a0);
            a1 = fmaf(hn[k + 1], w[k + 1], a1);
            a2 = fmaf(hn[k + 2], w[k + 2], a2);
            a3 = fmaf(hn[k + 3], w[k + 3], a3);
        }
        pre[(size_t)n * H + j] = (a0 + a1) + (a2 + a3) + bj;
    }
}

// ---------------- per-edge MLP: gather 2x64f, fused relu+64->32, 32->6 -------
__global__ void __launch_bounds__(256) edge_mlp(
    const float* __restrict__ pre,
    const int* __restrict__ src, const int* __restrict__ dst,
    const float* __restrict__ W2t, const float* __restrict__ b2,
    const float* __restrict__ W3t, const float* __restrict__ b3,
    float* __restrict__ out, int E)
{
    int e = blockIdx.x * 256 + threadIdx.x;
    if (e >= E) return;

    const float* pa = pre + (size_t)src[e] * H;        // src half, b1 pre-folded
    const float* pb = pre + (size_t)dst[e] * H + 64;   // dst half

    float z[32];
#pragma unroll
    for (int j = 0; j < 32; j++) z[j] = b2[j];

    // Layer 1 (add halves + relu) fused into layer 2 accumulation; y never stored.
#pragma unroll 4
    for (int k = 0; k < 64; k += 4) {
        float4 va = *(const float4*)(pa + k);
        float4 vb = *(const float4*)(pb + k);
        float y0 = fmaxf(va.x + vb.x, 0.f);
        float y1 = fmaxf(va.y + vb.y, 0.f);
        float y2 = fmaxf(va.z + vb.z, 0.f);
        float y3 = fmaxf(va.w + vb.w, 0.f);
        const float* w0 = W2t + k * 32;                 // wave-uniform -> s_load
#pragma unroll
        for (int j = 0; j < 32; j++) {
            float zj = z[j];
            zj = fmaf(y0, w0[j], zj);
            zj = fmaf(y1, w0[32 + j], zj);
            zj = fmaf(y2, w0[64 + j], zj);
            zj = fmaf(y3, w0[96 + j], zj);
            z[j] = zj;
        }
    }

    float o[6];
#pragma unroll
    for (int j = 0; j < 6; j++) o[j] = b3[j];
#pragma unroll
    for (int k = 0; k < 32; k++) {
        float zk = fmaxf(z[k], 0.f);
#pragma unroll
        for (int j = 0; j < 6; j++) o[j] = fmaf(zk, W3t[k * 6 + j], o[j]);
    }

    // 24 B/edge, 8-byte aligned -> three dwordx2 stores, contiguous across lanes
    float2* o2 = (float2*)(out + (size_t)e * 6);
    o2[0] = make_float2(o[0], o[1]);
    o2[1] = make_float2(o[2], o[3]);
    o2[2] = make_float2(o[4], o[5]);
}

extern "C" void kernel_launch(void* const* d_in, const int* in_sizes, int n_in,
                              void* d_out, int out_size, void* d_ws, size_t ws_size,
                              hipStream_t stream) {
    const float* h   = (const float*)d_in[0];
    const int*   src = (const int*)d_in[1];
    const int*   dst = (const int*)d_in[2];
    const float* W1  = (const float*)d_in[3];
    const float* b1  = (const float*)d_in[4];
    const float* W2  = (const float*)d_in[5];
    const float* b2  = (const float*)d_in[6];
    const float* W3  = (const float*)d_in[7];
    const float* b3  = (const float*)d_in[8];

    const int N = in_sizes[0] / H;      // 100000
    const int E = in_sizes[1];          // 1600000

    // Workspace layout (re-derived every call; ws is re-poisoned between calls)
    char* ws = (char*)d_ws;
    float* Wct = (float*)ws;                    // 64 KiB
    float* W2t = (float*)(ws + 64 * 1024);      // 8 KiB
    float* W3t = (float*)(ws + 72 * 1024);      // 768 B
    float* pre = (float*)(ws + 128 * 1024);     // N*128*4 = 51.2 MB

    prep_weights<<<32, 256, 0, stream>>>(W1, W2, W3, Wct, W2t, W3t);
    node_precompute<<<2048, 256, 0, stream>>>(h, Wct, b1, pre, N);
    edge_mlp<<<(E + 255) / 256, 256, 0, stream>>>(pre, src, dst, W2t, b2, W3t, b3,
                                                  (float*)d_out, E);
}

// Round 2
// 669.250 us; speedup vs baseline: 1.5907x; 1.5907x over previous
//
#include <hip/hip_runtime.h>

// Problem: per-edge MLP  out = relu(relu([h[src],h[dst]] @ W1.T + b1) @ W2.T + b2) @ W3.T + b3
// N=100000 nodes, H=128, E=1.6M edges, layers 256->64->32->6, all fp32.
//
// Strategy: layer 1 is linear over the concat, so precompute per-node
//   pre[n][j]    = sum_k h[n][k] * W1[j][k]       + b1[j]   (j<64, "src half", b1 folded)
//   pre[n][64+j] = sum_k h[n][k] * W1[j][128+k]             ("dst half")
// Then per edge: y[j] = pre[src][j] + pre[dst][64+j]; relu; 64->32->6 dense in registers.
// Cuts FLOPs 59.6G -> ~10.7G (no fp32 MFMA on CDNA4, so FLOP count is the ceiling).
//
// R2: node_precompute was spilling w[128] to scratch (VGPR_Count=64, FETCH 1.8GB).
//     __launch_bounds__(256,1) lifts the VGPR budget; float4 h-row loads cut
//     load-issue 4x. Predicted: 710us -> ~30us for this dispatch.

#define H 128

// ---------------- weight prep: transposes so inner loops read contiguous, ----
// ---------------- wave-uniform rows -----------------------------------------
__global__ void prep_weights(const float* __restrict__ W1,
                             const float* __restrict__ W2,
                             const float* __restrict__ W3,
                             float* __restrict__ Wct,   // [128][128]: Wct[k][j] = concat-W1 column
                             float* __restrict__ W2t,   // [64][32]:  W2t[k][j] = W2[j][k]
                             float* __restrict__ W3t)   // [32][6]:   W3t[k][j] = W3[j][k]
{
    int t = blockIdx.x * blockDim.x + threadIdx.x;
    int stride = gridDim.x * blockDim.x;
    // Wct[k*128+j]: j<64 -> W1[j][k] ; j>=64 -> W1[j-64][128+k]
    for (int i = t; i < 128 * 128; i += stride) {
        int k = i >> 7, j = i & 127;
        Wct[i] = (j < 64) ? W1[j * 256 + k] : W1[(j - 64) * 256 + 128 + k];
    }
    for (int i = t; i < 64 * 32; i += stride) {
        int k = i >> 5, j = i & 31;
        W2t[i] = W2[j * 64 + k];
    }
    for (int i = t; i < 32 * 6; i += stride) {
        int k = i / 6, j = i - k * 6;
        W3t[i] = W3[j * 32 + k];
    }
}

// ---------------- per-node precompute: pre = h @ Wct (+ b1 on first half) ----
// Block = 256 threads = 2 nodes/iter (j = tid&127 selects output column).
// Each thread pins its Wct column in 128 VGPRs. __launch_bounds__(256,1)
// allows up to 512 VGPR/wave so w[] stays register-resident (R1: it spilled
// at the default budget -> 1.8GB scratch traffic, 710us).
__global__ void __launch_bounds__(256, 1) node_precompute(
    const float* __restrict__ h,
    const float* __restrict__ Wct,
    const float* __restrict__ b1,
    float* __restrict__ pre, int N)
{
    const int j = threadIdx.x & 127;
    const int half = threadIdx.x >> 7;
    float w[H];
#pragma unroll
    for (int k = 0; k < H; k++) w[k] = Wct[k * 128 + j];
    const float bj = (j < 64) ? b1[j] : 0.f;

    for (int n = blockIdx.x * 2 + half; n < N; n += gridDim.x * 2) {
        const float4* hn4 = (const float4*)(h + (size_t)n * H);
        float a0 = 0.f, a1 = 0.f, a2 = 0.f, a3 = 0.f;   // 4 chains for FMA-latency ILP
#pragma unroll
        for (int kk = 0; kk < H / 4; kk++) {
            float4 hv = hn4[kk];   // same addr across lanes -> broadcast, L1-served
            a0 = fmaf(hv.x, w[4 * kk + 0], a0);
            a1 = fmaf(hv.y, w[4 * kk + 1], a1);
            a2 = fmaf(hv.z, w[4 * kk + 2], a2);
            a3 = fmaf(hv.w, w[4 * kk + 3], a3);
        }
        pre[(size_t)n * H + j] = (a0 + a1) + (a2 + a3) + bj;
    }
}

// ---------------- per-edge MLP: gather 2x64f, fused relu+64->32, 32->6 -------
__global__ void __launch_bounds__(256) edge_mlp(
    const float* __restrict__ pre,
    const int* __restrict__ src, const int* __restrict__ dst,
    const float* __restrict__ W2t, const float* __restrict__ b2,
    const float* __restrict__ W3t, const float* __restrict__ b3,
    float* __restrict__ out, int E)
{
    int e = blockIdx.x * 256 + threadIdx.x;
    if (e >= E) return;

    const float* pa = pre + (size_t)src[e] * H;        // src half, b1 pre-folded
    const float* pb = pre + (size_t)dst[e] * H + 64;   // dst half

    float z[32];
#pragma unroll
    for (int j = 0; j < 32; j++) z[j] = b2[j];

    // Layer 1 (add halves + relu) fused into layer 2 accumulation; y never stored.
#pragma unroll 4
    for (int k = 0; k < 64; k += 4) {
        float4 va = *(const float4*)(pa + k);
        float4 vb = *(const float4*)(pb + k);
        float y0 = fmaxf(va.x + vb.x, 0.f);
        float y1 = fmaxf(va.y + vb.y, 0.f);
        float y2 = fmaxf(va.z + vb.z, 0.f);
        float y3 = fmaxf(va.w + vb.w, 0.f);
        const float* w0 = W2t + k * 32;                 // wave-uniform address
#pragma unroll
        for (int j = 0; j < 32; j++) {
            float zj = z[j];
            zj = fmaf(y0, w0[j], zj);
            zj = fmaf(y1, w0[32 + j], zj);
            zj = fmaf(y2, w0[64 + j], zj);
            zj = fmaf(y3, w0[96 + j], zj);
            z[j] = zj;
        }
    }

    float o[6];
#pragma unroll
    for (int j = 0; j < 6; j++) o[j] = b3[j];
#pragma unroll
    for (int k = 0; k < 32; k++) {
        float zk = fmaxf(z[k], 0.f);
#pragma unroll
        for (int j = 0; j < 6; j++) o[j] = fmaf(zk, W3t[k * 6 + j], o[j]);
    }

    // 24 B/edge, 8-byte aligned -> three dwordx2 stores, contiguous across lanes
    float2* o2 = (float2*)(out + (size_t)e * 6);
    o2[0] = make_float2(o[0], o[1]);
    o2[1] = make_float2(o[2], o[3]);
    o2[2] = make_float2(o[4], o[5]);
}

extern "C" void kernel_launch(void* const* d_in, const int* in_sizes, int n_in,
                              void* d_out, int out_size, void* d_ws, size_t ws_size,
                              hipStream_t stream) {
    const float* h   = (const float*)d_in[0];
    const int*   src = (const int*)d_in[1];
    const int*   dst = (const int*)d_in[2];
    const float* W1  = (const float*)d_in[3];
    const float* b1  = (const float*)d_in[4];
    const float* W2  = (const float*)d_in[5];
    const float* b2  = (const float*)d_in[6];
    const float* W3  = (const float*)d_in[7];
    const float* b3  = (const float*)d_in[8];

    const int N = in_sizes[0] / H;      // 100000
    const int E = in_sizes[1];          // 1600000

    // Workspace layout (re-derived every call; ws is re-poisoned between calls)
    char* ws = (char*)d_ws;
    float* Wct = (float*)ws;                    // 64 KiB
    float* W2t = (float*)(ws + 64 * 1024);      // 8 KiB
    float* W3t = (float*)(ws + 72 * 1024);      // 768 B
    float* pre = (float*)(ws + 128 * 1024);     // N*128*4 = 51.2 MB

    prep_weights<<<32, 256, 0, stream>>>(W1, W2, W3, Wct, W2t, W3t);
    node_precompute<<<2048, 256, 0, stream>>>(h, Wct, b1, pre, N);
    edge_mlp<<<(E + 255) / 256, 256, 0, stream>>>(pre, src, dst, W2t, b2, W3t, b3,
                                                  (float*)d_out, E);
}

// Round 3
// 573.574 us; speedup vs baseline: 1.8561x; 1.1668x over previous
//
#include <hip/hip_runtime.h>
#include <stdint.h>

// Per-edge MLP  out = relu(relu([h[src],h[dst]] @ W1.T + b1) @ W2.T + b2) @ W3.T + b3
// N=100000, H=128, E=1.6M, layers 256->64->32->6, fp32 in/out.
//
// Layer 1 is linear over the concat -> precompute per node (b1 folded into src half):
//   pre[n][j]    = sum_k h[n][k] W1[j][k] + b1[j]   (j<64)
//   pre[n][64+j] = sum_k h[n][k] W1[j][128+k]
// pre is stored BF16 (25.6 MB, L3-resident; halves gather traffic; adds ~1e-3 err
// vs 9.3e-3 threshold).
//
// R3 changes:
//  - node_precompute: 8 nodes/iter amortizes weight access 8x (R2: compiler
//    rematerialized w[] loads per node -> issue-bound, 13% VALU, 307us).
//  - edge_mlp: 2 edges/thread, W2 in LDS quad layout (ds_read_b128 broadcast
//    feeds 8 FMAs), W3/b2/b3 in LDS, raw bf16 gather rows held in VGPRs.

#define H 128

// ---------------- weight prep ------------------------------------------------
__global__ void prep_weights(const float* __restrict__ W1,
                             const float* __restrict__ W2,
                             float* __restrict__ WctT,  // [128 j][128 k] concat-W1 rows
                             float* __restrict__ W2q)   // [16 q][32 j][4] quads along k
{
    int t = blockIdx.x * blockDim.x + threadIdx.x;
    int stride = gridDim.x * blockDim.x;
    for (int i = t; i < 128 * 128; i += stride) {
        int j = i >> 7, k = i & 127;
        WctT[i] = (j < 64) ? W1[j * 256 + k] : W1[(j - 64) * 256 + 128 + k];
    }
    for (int i = t; i < 2048; i += stride) {
        int tt = i & 3; int qj = i >> 2; int j = qj & 31; int q = qj >> 5;
        W2q[i] = W2[j * 64 + q * 4 + tt];
    }
}

__device__ __forceinline__ uint16_t f2bf(float f) {           // RNE fp32->bf16
    uint32_t u = __float_as_uint(f);
    return (uint16_t)((u + 0x7fffu + ((u >> 16) & 1u)) >> 16);
}
__device__ __forceinline__ float bf_lo(uint32_t u) { return __uint_as_float(u << 16); }
__device__ __forceinline__ float bf_hi(uint32_t u) { return __uint_as_float(u & 0xffff0000u); }

// ---------------- per-node precompute: pre = h @ WctT.T (+b1), bf16 out ------
// j = tid&127 owns one output column; 8 nodes per iteration so the Wct column
// access (register-resident or L1-rematerialized) amortizes 8x.
__global__ void __launch_bounds__(256, 1) node_precompute(
    const float* __restrict__ h,
    const float* __restrict__ WctT,
    const float* __restrict__ b1,
    uint16_t* __restrict__ pre, int N)
{
    const int j = threadIdx.x & 127;
    const int half = threadIdx.x >> 7;
    const float4* WT4 = (const float4*)(WctT + (size_t)j * H);  // row j, contiguous

    float4 w[32];
#pragma unroll
    for (int kk = 0; kk < 32; kk++) w[kk] = WT4[kk];
    const float bj = (j < 64) ? b1[j] : 0.f;

    const int n0 = (blockIdx.x * 2 + half) * 8;
    if (n0 >= N) return;

    if (n0 + 8 <= N) {
        float acc[8];
#pragma unroll
        for (int t = 0; t < 8; t++) acc[t] = 0.f;
#pragma unroll
        for (int kk = 0; kk < 32; kk++) {
            float4 wv = w[kk];
#pragma unroll
            for (int t = 0; t < 8; t++) {
                float4 hv = *(const float4*)(h + (size_t)(n0 + t) * H + kk * 4);
                acc[t] = fmaf(hv.x, wv.x, fmaf(hv.y, wv.y,
                         fmaf(hv.z, wv.z, fmaf(hv.w, wv.w, acc[t]))));
            }
        }
#pragma unroll
        for (int t = 0; t < 8; t++)
            pre[(size_t)(n0 + t) * H + j] = f2bf(acc[t] + bj);
    } else {
        for (int t = 0; t < 8 && n0 + t < N; t++) {
            float a = 0.f;
            for (int kk = 0; kk < 32; kk++) {
                float4 hv = *(const float4*)(h + (size_t)(n0 + t) * H + kk * 4);
                float4 wv = w[kk];
                a = fmaf(hv.x, wv.x, fmaf(hv.y, wv.y,
                    fmaf(hv.z, wv.z, fmaf(hv.w, wv.w, a))));
            }
            pre[(size_t)(n0 + t) * H + j] = f2bf(a + bj);
        }
    }
}

// ---------------- per-edge MLP ----------------------------------------------
// 2 edges/thread. Raw bf16 gather rows (4 x 128B) live in 32 uint4 VGPRs.
// W2 quads from LDS: lane-uniform address -> broadcast, 1 ds_read_b128 / 8 FMA.
__global__ void __launch_bounds__(256, 2) edge_mlp(
    const uint16_t* __restrict__ pre,
    const int* __restrict__ src, const int* __restrict__ dst,
    const float* __restrict__ W2q, const float* __restrict__ b2,
    const float* __restrict__ W3, const float* __restrict__ b3,
    float* __restrict__ out, int E)
{
    __shared__ float4 sW2[512];   // [q*32+j] -> W2[j][4q..4q+3]
    __shared__ float4 sW3[48];    // [c*8+ko] -> W3[c][4ko..4ko+3]
    __shared__ float  sb2[32];
    __shared__ float  sb3[6];

    const int tid = threadIdx.x;
    {
        const float4* W2q4 = (const float4*)W2q;
        sW2[tid]       = W2q4[tid];
        sW2[tid + 256] = W2q4[tid + 256];
        if (tid < 48) sW3[tid] = ((const float4*)W3)[tid];
        if (tid < 32) sb2[tid] = b2[tid];
        if (tid < 6)  sb3[tid] = b3[tid];
    }
    __syncthreads();

    const int e0 = (blockIdx.x * 256 + tid) * 2;
    if (e0 >= E) return;                       // no syncs below; E is even

    const int s0 = src[e0], s1 = src[e0 + 1];
    const int d0 = dst[e0], d1 = dst[e0 + 1];

    // Gather: src-half = row quads 0..7, dst-half = row quads 8..15 (bf16).
    const uint4* A0 = (const uint4*)(pre + (size_t)s0 * H);
    const uint4* B0 = (const uint4*)(pre + (size_t)d0 * H);
    const uint4* A1 = (const uint4*)(pre + (size_t)s1 * H);
    const uint4* B1 = (const uint4*)(pre + (size_t)d1 * H);
    uint4 ra0[8], rb0[8], ra1[8], rb1[8];
#pragma unroll
    for (int i = 0; i < 8; i++) { ra0[i] = A0[i]; rb0[i] = B0[8 + i]; }
#pragma unroll
    for (int i = 0; i < 8; i++) { ra1[i] = A1[i]; rb1[i] = B1[8 + i]; }

    float z0[32], z1[32];
#pragma unroll
    for (int j = 0; j < 32; j++) { z0[j] = sb2[j]; z1[j] = sb2[j]; }

#pragma unroll
    for (int q = 0; q < 16; q++) {
        const int o = q >> 1;
        uint32_t a0u0, a0u1, b0u0, b0u1, a1u0, a1u1, b1u0, b1u1;
        if (q & 1) {
            a0u0 = ra0[o].z; a0u1 = ra0[o].w; b0u0 = rb0[o].z; b0u1 = rb0[o].w;
            a1u0 = ra1[o].z; a1u1 = ra1[o].w; b1u0 = rb1[o].z; b1u1 = rb1[o].w;
        } else {
            a0u0 = ra0[o].x; a0u1 = ra0[o].y; b0u0 = rb0[o].x; b0u1 = rb0[o].y;
            a1u0 = ra1[o].x; a1u1 = ra1[o].y; b1u0 = rb1[o].x; b1u1 = rb1[o].y;
        }
        const float y00 = fmaxf(bf_lo(a0u0) + bf_lo(b0u0), 0.f);
        const float y01 = fmaxf(bf_hi(a0u0) + bf_hi(b0u0), 0.f);
        const float y02 = fmaxf(bf_lo(a0u1) + bf_lo(b0u1), 0.f);
        const float y03 = fmaxf(bf_hi(a0u1) + bf_hi(b0u1), 0.f);
        const float y10 = fmaxf(bf_lo(a1u0) + bf_lo(b1u0), 0.f);
        const float y11 = fmaxf(bf_hi(a1u0) + bf_hi(b1u0), 0.f);
        const float y12 = fmaxf(bf_lo(a1u1) + bf_lo(b1u1), 0.f);
        const float y13 = fmaxf(bf_hi(a1u1) + bf_hi(b1u1), 0.f);
#pragma unroll
        for (int j = 0; j < 32; j++) {
            float4 w = sW2[q * 32 + j];
            z0[j] = fmaf(y00, w.x, fmaf(y01, w.y, fmaf(y02, w.z, fmaf(y03, w.w, z0[j]))));
            z1[j] = fmaf(y10, w.x, fmaf(y11, w.y, fmaf(y12, w.z, fmaf(y13, w.w, z1[j]))));
        }
    }

#pragma unroll
    for (int j = 0; j < 32; j++) { z0[j] = fmaxf(z0[j], 0.f); z1[j] = fmaxf(z1[j], 0.f); }

    float o0[6], o1[6];
#pragma unroll
    for (int c = 0; c < 6; c++) { o0[c] = sb3[c]; o1[c] = sb3[c]; }
#pragma unroll
    for (int c = 0; c < 6; c++) {
#pragma unroll
        for (int ko = 0; ko < 8; ko++) {
            float4 w = sW3[c * 8 + ko];
            o0[c] = fmaf(z0[4*ko], w.x, fmaf(z0[4*ko+1], w.y,
                    fmaf(z0[4*ko+2], w.z, fmaf(z0[4*ko+3], w.w, o0[c]))));
            o1[c] = fmaf(z1[4*ko], w.x, fmaf(z1[4*ko+1], w.y,
                    fmaf(z1[4*ko+2], w.z, fmaf(z1[4*ko+3], w.w, o1[c]))));
        }
    }

    // 2 edges x 6 floats = 48 consecutive, 16B-aligned bytes -> 3 dwordx4 stores
    float4* ov = (float4*)(out + (size_t)e0 * 6);
    ov[0] = make_float4(o0[0], o0[1], o0[2], o0[3]);
    ov[1] = make_float4(o0[4], o0[5], o1[0], o1[1]);
    ov[2] = make_float4(o1[2], o1[3], o1[4], o1[5]);
}

extern "C" void kernel_launch(void* const* d_in, const int* in_sizes, int n_in,
                              void* d_out, int out_size, void* d_ws, size_t ws_size,
                              hipStream_t stream) {
    const float* h   = (const float*)d_in[0];
    const int*   src = (const int*)d_in[1];
    const int*   dst = (const int*)d_in[2];
    const float* W1  = (const float*)d_in[3];
    const float* b1  = (const float*)d_in[4];
    const float* W2  = (const float*)d_in[5];
    const float* b2  = (const float*)d_in[6];
    const float* W3  = (const float*)d_in[7];
    const float* b3  = (const float*)d_in[8];

    const int N = in_sizes[0] / H;      // 100000
    const int E = in_sizes[1];          // 1600000

    char* ws = (char*)d_ws;
    float*    WctT = (float*)ws;                    // 64 KiB
    float*    W2q  = (float*)(ws + 64 * 1024);      // 8 KiB
    uint16_t* pre  = (uint16_t*)(ws + 128 * 1024);  // N*128*2 = 25.6 MB (bf16)

    prep_weights<<<64, 256, 0, stream>>>(W1, W2, WctT, W2q);
    node_precompute<<<(N + 15) / 16, 256, 0, stream>>>(h, WctT, b1, pre, N);
    edge_mlp<<<(E + 511) / 512, 256, 0, stream>>>(pre, src, dst, W2q, b2, W3, b3,
                                                  (float*)d_out, E);
}

// Round 4
// 321.491 us; speedup vs baseline: 3.3115x; 1.7841x over previous
//
#include <hip/hip_runtime.h>
#include <stdint.h>

// Per-edge MLP  out = relu(relu([h[src],h[dst]] @ W1.T + b1) @ W2.T + b2) @ W3.T + b3
// N=100000, H=128, E=1.6M, layers 256->64->32->6, fp32 in/out.
//
// Layer 1 is linear over the concat -> precompute per node (b1 folded into src half):
//   pre[n][j]    = sum_k h[n][k] W1[j][k] + b1[j]   (j<64)
//   pre[n][64+j] = sum_k h[n][k] W1[j][128+k]
// pre stored bf16 (25.6 MB, L3-resident).
//
// R4: precompute rewritten as an MFMA bf16 GEMM (R2/R3: the VALU version kept
// losing to the register allocator -> weight reloads, 64 lines/wave-load,
// 15% VALU, 290us). One wave = 16 nodes x 128 cols: A-frags converted from
// fp32 h in-register; B prepped in exact 16x16x32 B-fragment order (32KB,
// L2-resident, coalesced uint4 loads). C/D layout: col=lane&15,
// row=(lane>>4)*4+reg (learn_hip m89/m91). edge_mlp unchanged this round.

#define H 128

typedef short bf16x8 __attribute__((ext_vector_type(8)));
typedef float f32x4  __attribute__((ext_vector_type(4)));

__device__ __forceinline__ uint16_t f2bf(float f) {           // RNE fp32->bf16
    uint32_t u = __float_as_uint(f);
    return (uint16_t)((u + 0x7fffu + ((u >> 16) & 1u)) >> 16);
}
__device__ __forceinline__ float bf_lo(uint32_t u) { return __uint_as_float(u << 16); }
__device__ __forceinline__ float bf_hi(uint32_t u) { return __uint_as_float(u & 0xffff0000u); }

// ---------------- weight prep ------------------------------------------------
// Bfrag: concat-W1 as bf16 in 16x16x32 B-fragment order:
//   element i = ((kt*8 + nt)*64 + lane)*8 + j  ->  B[k][n],
//   k = kt*32 + (lane>>4)*8 + j,  n = nt*16 + (lane&15)
//   B[k][n] = n<64 ? W1[n][k] : W1[n-64][128+k]
// W2q: [16 q][32 j][4] fp32 quads along k for the edge kernel (unchanged).
__global__ void prep_weights(const float* __restrict__ W1,
                             const float* __restrict__ W2,
                             uint16_t* __restrict__ Bfrag,
                             float* __restrict__ W2q)
{
    int t = blockIdx.x * blockDim.x + threadIdx.x;
    int stride = gridDim.x * blockDim.x;
    for (int i = t; i < 4 * 8 * 64 * 8; i += stride) {
        int j    = i & 7;
        int lane = (i >> 3) & 63;
        int nt   = (i >> 9) & 7;
        int kt   = (i >> 12);
        int k = kt * 32 + (lane >> 4) * 8 + j;
        int n = nt * 16 + (lane & 15);
        float v = (n < 64) ? W1[n * 256 + k] : W1[(n - 64) * 256 + 128 + k];
        Bfrag[i] = f2bf(v);
    }
    for (int i = t; i < 2048; i += stride) {
        int tt = i & 3; int qj = i >> 2; int j = qj & 31; int q = qj >> 5;
        W2q[i] = W2[j * 64 + q * 4 + tt];
    }
}

// ---------------- per-node precompute: pre = h @ Wct (+b1), MFMA ------------
// Block = 4 waves = 64 nodes. Per wave: M=16 nodes, N=128 (8 ntiles), K=128
// (4 chained 16x16x32 MFMAs per ntile).
__global__ void __launch_bounds__(256) node_gemm(
    const float* __restrict__ h,
    const uint16_t* __restrict__ Bfrag,
    const float* __restrict__ b1,
    uint16_t* __restrict__ pre, int N)
{
    const int wave = threadIdx.x >> 6;
    const int lane = threadIdx.x & 63;
    const int n0 = (blockIdx.x * 4 + wave) * 16;
    if (n0 >= N) return;

    const int m    = lane & 15;
    const int quad = lane >> 4;

    int arow = n0 + m; if (arow >= N) arow = N - 1;   // clamp (stores guarded)
    const float* hrow = h + (size_t)arow * H + quad * 8;

    // A fragments: A[m=lane&15][k=quad*8+j], 4 ktiles, fp32->bf16 RNE in-reg.
    bf16x8 afr[4];
#pragma unroll
    for (int kt = 0; kt < 4; kt++) {
        float4 lo = *(const float4*)(hrow + kt * 32);
        float4 hi = *(const float4*)(hrow + kt * 32 + 4);
        bf16x8 a;
        a[0] = (short)f2bf(lo.x); a[1] = (short)f2bf(lo.y);
        a[2] = (short)f2bf(lo.z); a[3] = (short)f2bf(lo.w);
        a[4] = (short)f2bf(hi.x); a[5] = (short)f2bf(hi.y);
        a[6] = (short)f2bf(hi.z); a[7] = (short)f2bf(hi.w);
        afr[kt] = a;
    }

#pragma unroll
    for (int nt = 0; nt < 8; nt++) {
        f32x4 acc = {0.f, 0.f, 0.f, 0.f};
#pragma unroll
        for (int kt = 0; kt < 4; kt++) {
            bf16x8 bfr = *(const bf16x8*)(Bfrag + ((size_t)(kt * 8 + nt) * 64 + lane) * 8);
            acc = __builtin_amdgcn_mfma_f32_16x16x32_bf16(afr[kt], bfr, acc, 0, 0, 0);
        }
        const int ncol = nt * 16 + m;                 // output feature (C col)
        const float bv = (ncol < 64) ? b1[ncol] : 0.f;
#pragma unroll
        for (int r = 0; r < 4; r++) {
            const int node = n0 + quad * 4 + r;       // C row
            if (node < N)
                pre[(size_t)node * H + ncol] = f2bf(acc[r] + bv);
        }
    }
}

// ---------------- per-edge MLP (unchanged from R3) ---------------------------
// 2 edges/thread. Raw bf16 gather rows (4 x 128B) live in 32 uint4 VGPRs.
// W2 quads from LDS: lane-uniform address -> broadcast, 1 ds_read_b128 / 8 FMA.
__global__ void __launch_bounds__(256, 2) edge_mlp(
    const uint16_t* __restrict__ pre,
    const int* __restrict__ src, const int* __restrict__ dst,
    const float* __restrict__ W2q, const float* __restrict__ b2,
    const float* __restrict__ W3, const float* __restrict__ b3,
    float* __restrict__ out, int E)
{
    __shared__ float4 sW2[512];   // [q*32+j] -> W2[j][4q..4q+3]
    __shared__ float4 sW3[48];    // [c*8+ko] -> W3[c][4ko..4ko+3]
    __shared__ float  sb2[32];
    __shared__ float  sb3[6];

    const int tid = threadIdx.x;
    {
        const float4* W2q4 = (const float4*)W2q;
        sW2[tid]       = W2q4[tid];
        sW2[tid + 256] = W2q4[tid + 256];
        if (tid < 48) sW3[tid] = ((const float4*)W3)[tid];
        if (tid < 32) sb2[tid] = b2[tid];
        if (tid < 6)  sb3[tid] = b3[tid];
    }
    __syncthreads();

    const int e0 = (blockIdx.x * 256 + tid) * 2;
    if (e0 >= E) return;                       // no syncs below; E is even

    const int s0 = src[e0], s1 = src[e0 + 1];
    const int d0 = dst[e0], d1 = dst[e0 + 1];

    // Gather: src-half = row quads 0..7, dst-half = row quads 8..15 (bf16).
    const uint4* A0 = (const uint4*)(pre + (size_t)s0 * H);
    const uint4* B0 = (const uint4*)(pre + (size_t)d0 * H);
    const uint4* A1 = (const uint4*)(pre + (size_t)s1 * H);
    const uint4* B1 = (const uint4*)(pre + (size_t)d1 * H);
    uint4 ra0[8], rb0[8], ra1[8], rb1[8];
#pragma unroll
    for (int i = 0; i < 8; i++) { ra0[i] = A0[i]; rb0[i] = B0[8 + i]; }
#pragma unroll
    for (int i = 0; i < 8; i++) { ra1[i] = A1[i]; rb1[i] = B1[8 + i]; }

    float z0[32], z1[32];
#pragma unroll
    for (int j = 0; j < 32; j++) { z0[j] = sb2[j]; z1[j] = sb2[j]; }

#pragma unroll
    for (int q = 0; q < 16; q++) {
        const int o = q >> 1;
        uint32_t a0u0, a0u1, b0u0, b0u1, a1u0, a1u1, b1u0, b1u1;
        if (q & 1) {
            a0u0 = ra0[o].z; a0u1 = ra0[o].w; b0u0 = rb0[o].z; b0u1 = rb0[o].w;
            a1u0 = ra1[o].z; a1u1 = ra1[o].w; b1u0 = rb1[o].z; b1u1 = rb1[o].w;
        } else {
            a0u0 = ra0[o].x; a0u1 = ra0[o].y; b0u0 = rb0[o].x; b0u1 = rb0[o].y;
            a1u0 = ra1[o].x; a1u1 = ra1[o].y; b1u0 = rb1[o].x; b1u1 = rb1[o].y;
        }
        const float y00 = fmaxf(bf_lo(a0u0) + bf_lo(b0u0), 0.f);
        const float y01 = fmaxf(bf_hi(a0u0) + bf_hi(b0u0), 0.f);
        const float y02 = fmaxf(bf_lo(a0u1) + bf_lo(b0u1), 0.f);
        const float y03 = fmaxf(bf_hi(a0u1) + bf_hi(b0u1), 0.f);
        const float y10 = fmaxf(bf_lo(a1u0) + bf_lo(b1u0), 0.f);
        const float y11 = fmaxf(bf_hi(a1u0) + bf_hi(b1u0), 0.f);
        const float y12 = fmaxf(bf_lo(a1u1) + bf_lo(b1u1), 0.f);
        const float y13 = fmaxf(bf_hi(a1u1) + bf_hi(b1u1), 0.f);
#pragma unroll
        for (int j = 0; j < 32; j++) {
            float4 w = sW2[q * 32 + j];
            z0[j] = fmaf(y00, w.x, fmaf(y01, w.y, fmaf(y02, w.z, fmaf(y03, w.w, z0[j]))));
            z1[j] = fmaf(y10, w.x, fmaf(y11, w.y, fmaf(y12, w.z, fmaf(y13, w.w, z1[j]))));
        }
    }

#pragma unroll
    for (int j = 0; j < 32; j++) { z0[j] = fmaxf(z0[j], 0.f); z1[j] = fmaxf(z1[j], 0.f); }

    float o0[6], o1[6];
#pragma unroll
    for (int c = 0; c < 6; c++) { o0[c] = sb3[c]; o1[c] = sb3[c]; }
#pragma unroll
    for (int c = 0; c < 6; c++) {
#pragma unroll
        for (int ko = 0; ko < 8; ko++) {
            float4 w = sW3[c * 8 + ko];
            o0[c] = fmaf(z0[4*ko], w.x, fmaf(z0[4*ko+1], w.y,
                    fmaf(z0[4*ko+2], w.z, fmaf(z0[4*ko+3], w.w, o0[c]))));
            o1[c] = fmaf(z1[4*ko], w.x, fmaf(z1[4*ko+1], w.y,
                    fmaf(z1[4*ko+2], w.z, fmaf(z1[4*ko+3], w.w, o1[c]))));
        }
    }

    // 2 edges x 6 floats = 48 consecutive, 16B-aligned bytes -> 3 dwordx4 stores
    float4* ov = (float4*)(out + (size_t)e0 * 6);
    ov[0] = make_float4(o0[0], o0[1], o0[2], o0[3]);
    ov[1] = make_float4(o0[4], o0[5], o1[0], o1[1]);
    ov[2] = make_float4(o1[2], o1[3], o1[4], o1[5]);
}

extern "C" void kernel_launch(void* const* d_in, const int* in_sizes, int n_in,
                              void* d_out, int out_size, void* d_ws, size_t ws_size,
                              hipStream_t stream) {
    const float* h   = (const float*)d_in[0];
    const int*   src = (const int*)d_in[1];
    const int*   dst = (const int*)d_in[2];
    const float* W1  = (const float*)d_in[3];
    const float* b1  = (const float*)d_in[4];
    const float* W2  = (const float*)d_in[5];
    const float* b2  = (const float*)d_in[6];
    const float* W3  = (const float*)d_in[7];
    const float* b3  = (const float*)d_in[8];

    const int N = in_sizes[0] / H;      // 100000
    const int E = in_sizes[1];          // 1600000

    char* ws = (char*)d_ws;
    uint16_t* Bfrag = (uint16_t*)ws;                 // 32 KiB
    float*    W2q   = (float*)(ws + 64 * 1024);      // 8 KiB
    uint16_t* pre   = (uint16_t*)(ws + 128 * 1024);  // N*128*2 = 25.6 MB (bf16)

    prep_weights<<<64, 256, 0, stream>>>(W1, W2, Bfrag, W2q);
    node_gemm<<<(N + 63) / 64, 256, 0, stream>>>(h, Bfrag, b1, pre, N);
    edge_mlp<<<(E + 511) / 512, 256, 0, stream>>>(pre, src, dst, W2q, b2, W3, b3,
                                                  (float*)d_out, E);
}

// Round 5
// 188.300 us; speedup vs baseline: 5.6538x; 1.7073x over previous
//
#include <hip/hip_runtime.h>
#include <hip/hip_bf16.h>
#include <stdint.h>

// Per-edge MLP  out = relu(relu([h[src],h[dst]] @ W1.T + b1) @ W2.T + b2) @ W3.T + b3
// N=100000, H=128, E=1.6M, layers 256->64->32->6, fp32 in/out.
//
// Pipeline:
//  1) node_gemm (MFMA): pre[n] = [h@W1a.T + b1 , h@W1b.T]  bf16, 25.6 MB (L3-resident)
//  2) edge_mlp  (MFMA): per 16-edge tile, layer2 = 2x2 MFMAs (y formed in-lane from
//     gather -- gather layout == A-frag layout), z relu'd to bf16 in a wave-private
//     LDS slab laid out as layer-3 A-frags, layer3 = 1 MFMA (W3 cols 6..15 zero).
// All MFMA layouts are the m89/m91-verified 16x16x32_bf16 mappings:
//   A[m=lane&15][k=(lane>>4)*8+j], B[k=(lane>>4)*8+j][n=lane&15],
//   C/D: col=lane&15, row=(lane>>4)*4+reg.
//
// R5: edge_mlp moved from VALU (2048 FMA/edge, 51us floor, measured 215us at
// 49% VALUBusy) to MFMA; new floor is the 410 MB L2/L3 gather.

#define H 128

typedef short bf16x8 __attribute__((ext_vector_type(8)));
typedef float f32x4  __attribute__((ext_vector_type(4)));

__device__ __forceinline__ uint16_t f2bf(float f) {           // RNE fp32->bf16
    uint32_t u = __float_as_uint(f);
    return (uint16_t)((u + 0x7fffu + ((u >> 16) & 1u)) >> 16);
}
__device__ __forceinline__ float bf_lo(uint32_t u) { return __uint_as_float(u << 16); }
__device__ __forceinline__ float bf_hi(uint32_t u) { return __uint_as_float(u & 0xffff0000u); }
__device__ __forceinline__ uint32_t pk_bf16(float lo, float hi) {   // RNE pair pack
    __hip_bfloat162 v = __float22bfloat162_rn(float2{lo, hi});
    return *reinterpret_cast<uint32_t*>(&v);
}

// ---------------- weight prep ------------------------------------------------
// Bfrag (node_gemm): concat-W1 in B-frag order, 4 ktiles x 8 ntiles (32 KB).
// EFrag (edge_mlp): 5 frags x 64 lanes x 8 bf16 (5 KB):
//   f=kt*2+nt (f<4): layer2 B[k=kt*32+(lane>>4)*8+j][n=nt*16+(lane&15)] = W2[n][k]
//   f=4:             layer3 B[k=(lane>>4)*8+j][n=lane&15] = (n<6)? W3[n][k] : 0
__global__ void prep_weights(const float* __restrict__ W1,
                             const float* __restrict__ W2,
                             const float* __restrict__ W3,
                             uint16_t* __restrict__ Bfrag,
                             uint16_t* __restrict__ EFrag)
{
    int t = blockIdx.x * blockDim.x + threadIdx.x;
    int stride = gridDim.x * blockDim.x;
    for (int i = t; i < 4 * 8 * 64 * 8; i += stride) {
        int j    = i & 7;
        int lane = (i >> 3) & 63;
        int nt   = (i >> 9) & 7;
        int kt   = (i >> 12);
        int k = kt * 32 + (lane >> 4) * 8 + j;
        int n = nt * 16 + (lane & 15);
        float v = (n < 64) ? W1[n * 256 + k] : W1[(n - 64) * 256 + 128 + k];
        Bfrag[i] = f2bf(v);
    }
    for (int i = t; i < 5 * 64 * 8; i += stride) {
        int j    = i & 7;
        int lane = (i >> 3) & 63;
        int f    = i >> 9;
        uint16_t v;
        if (f < 4) {
            int kt = f >> 1, nt = f & 1;
            int k = kt * 32 + (lane >> 4) * 8 + j;
            int n = nt * 16 + (lane & 15);
            v = f2bf(W2[n * 64 + k]);
        } else {
            int k = (lane >> 4) * 8 + j;
            int n = lane & 15;
            v = (n < 6) ? f2bf(W3[n * 32 + k]) : (uint16_t)0;
        }
        EFrag[i] = v;
    }
}

// ---------------- per-node precompute (unchanged from R4) --------------------
__global__ void __launch_bounds__(256) node_gemm(
    const float* __restrict__ h,
    const uint16_t* __restrict__ Bfrag,
    const float* __restrict__ b1,
    uint16_t* __restrict__ pre, int N)
{
    const int wave = threadIdx.x >> 6;
    const int lane = threadIdx.x & 63;
    const int n0 = (blockIdx.x * 4 + wave) * 16;
    if (n0 >= N) return;

    const int m    = lane & 15;
    const int quad = lane >> 4;

    int arow = n0 + m; if (arow >= N) arow = N - 1;
    const float* hrow = h + (size_t)arow * H + quad * 8;

    bf16x8 afr[4];
#pragma unroll
    for (int kt = 0; kt < 4; kt++) {
        float4 lo = *(const float4*)(hrow + kt * 32);
        float4 hi = *(const float4*)(hrow + kt * 32 + 4);
        bf16x8 a;
        a[0] = (short)f2bf(lo.x); a[1] = (short)f2bf(lo.y);
        a[2] = (short)f2bf(lo.z); a[3] = (short)f2bf(lo.w);
        a[4] = (short)f2bf(hi.x); a[5] = (short)f2bf(hi.y);
        a[6] = (short)f2bf(hi.z); a[7] = (short)f2bf(hi.w);
        afr[kt] = a;
    }

#pragma unroll
    for (int nt = 0; nt < 8; nt++) {
        f32x4 acc = {0.f, 0.f, 0.f, 0.f};
#pragma unroll
        for (int kt = 0; kt < 4; kt++) {
            bf16x8 bfr = *(const bf16x8*)(Bfrag + ((size_t)(kt * 8 + nt) * 64 + lane) * 8);
            acc = __builtin_amdgcn_mfma_f32_16x16x32_bf16(afr[kt], bfr, acc, 0, 0, 0);
        }
        const int ncol = nt * 16 + m;
        const float bv = (ncol < 64) ? b1[ncol] : 0.f;
#pragma unroll
        for (int r = 0; r < 4; r++) {
            const int node = n0 + quad * 4 + r;
            if (node < N)
                pre[(size_t)node * H + ncol] = f2bf(acc[r] + bv);
        }
    }
}

// ---------------- per-edge MLP: MFMA layers 2+3 ------------------------------
// One wave handles 64 edges (4 subtiles of 16). Wave-private LDS slab holds z
// in bf16 [edge][feat] (stride 40 halves = 80 B, b128-aligned) -- written from
// layer-2 C-layout, read back directly as layer-3 A-frags. No barriers.
__global__ void __launch_bounds__(256, 2) edge_mlp(
    const uint16_t* __restrict__ pre,
    const int* __restrict__ src, const int* __restrict__ dst,
    const uint16_t* __restrict__ EFrag,
    const float* __restrict__ b2, const float* __restrict__ b3,
    float* __restrict__ out, long E)
{
    __shared__ uint16_t zbuf[4][64 * 40];

    const int wave = threadIdx.x >> 6;
    const int lane = threadIdx.x & 63;
    const int m15  = lane & 15;
    const int quad = lane >> 4;
    uint16_t* zw = &zbuf[wave][0];

    // Preload B-fragments (L2-hot, 16 B/lane each) and biases.
    bf16x8 bL2[4], bL3;
#pragma unroll
    for (int f = 0; f < 4; f++) bL2[f] = *(const bf16x8*)(EFrag + (f * 64 + lane) * 8);
    bL3 = *(const bf16x8*)(EFrag + (4 * 64 + lane) * 8);
    const float vb2a = b2[m15];
    const float vb2b = b2[16 + m15];
    const float vb3  = (m15 < 6) ? b3[m15] : 0.f;

    const long e0 = (long)(blockIdx.x * 4 + wave) * 64;
    if (e0 >= E) return;

    // ---------- layer 2: gather -> y (A-frags, in-lane) -> 2x2 MFMAs ----------
#pragma unroll
    for (int st = 0; st < 4; st++) {
        long e = e0 + st * 16 + m15;
        if (e >= E) e = E - 1;                       // tail clamp (stores guarded)
        const int se = src[e], de = dst[e];
        const uint16_t* pa = pre + (size_t)se * H;        // src half (b1 folded)
        const uint16_t* pb = pre + (size_t)de * H + 64;   // dst half

        bf16x8 afr[2];
#pragma unroll
        for (int kt = 0; kt < 2; kt++) {
            uint4 ua = *(const uint4*)(pa + kt * 32 + quad * 8);
            uint4 ub = *(const uint4*)(pb + kt * 32 + quad * 8);
            float y0 = fmaxf(bf_lo(ua.x) + bf_lo(ub.x), 0.f);
            float y1 = fmaxf(bf_hi(ua.x) + bf_hi(ub.x), 0.f);
            float y2 = fmaxf(bf_lo(ua.y) + bf_lo(ub.y), 0.f);
            float y3 = fmaxf(bf_hi(ua.y) + bf_hi(ub.y), 0.f);
            float y4 = fmaxf(bf_lo(ua.z) + bf_lo(ub.z), 0.f);
            float y5 = fmaxf(bf_hi(ua.z) + bf_hi(ub.z), 0.f);
            float y6 = fmaxf(bf_lo(ua.w) + bf_lo(ub.w), 0.f);
            float y7 = fmaxf(bf_hi(ua.w) + bf_hi(ub.w), 0.f);
            union { bf16x8 v; uint32_t u[4]; } A;
            A.u[0] = pk_bf16(y0, y1);
            A.u[1] = pk_bf16(y2, y3);
            A.u[2] = pk_bf16(y4, y5);
            A.u[3] = pk_bf16(y6, y7);
            afr[kt] = A.v;
        }

#pragma unroll
        for (int nt = 0; nt < 2; nt++) {
            f32x4 acc = {0.f, 0.f, 0.f, 0.f};
            acc = __builtin_amdgcn_mfma_f32_16x16x32_bf16(afr[0], bL2[0 * 2 + nt], acc, 0, 0, 0);
            acc = __builtin_amdgcn_mfma_f32_16x16x32_bf16(afr[1], bL2[1 * 2 + nt], acc, 0, 0, 0);
            const float vb2 = nt ? vb2b : vb2a;           // lane's n = nt*16+m15
#pragma unroll
            for (int r = 0; r < 4; r++) {
                float z = fmaxf(acc[r] + vb2, 0.f);
                int el = st * 16 + quad * 4 + r;          // C row = edge-in-round
                zw[el * 40 + nt * 16 + m15] = f2bf(z);
            }
        }
    }

    // ---------- layer 3: LDS A-frags -> 1 MFMA per subtile -------------------
#pragma unroll
    for (int st = 0; st < 4; st++) {
        bf16x8 a3 = *(const bf16x8*)(zw + (st * 16 + m15) * 40 + quad * 8);
        f32x4 o = {0.f, 0.f, 0.f, 0.f};
        o = __builtin_amdgcn_mfma_f32_16x16x32_bf16(a3, bL3, o, 0, 0, 0);
        if (m15 < 6) {
#pragma unroll
            for (int r = 0; r < 4; r++) {
                long e = e0 + st * 16 + quad * 4 + r;     // D row = edge, col = class
                if (e < E) out[e * 6 + m15] = o[r] + vb3;
            }
        }
    }
}

extern "C" void kernel_launch(void* const* d_in, const int* in_sizes, int n_in,
                              void* d_out, int out_size, void* d_ws, size_t ws_size,
                              hipStream_t stream) {
    const float* h   = (const float*)d_in[0];
    const int*   src = (const int*)d_in[1];
    const int*   dst = (const int*)d_in[2];
    const float* W1  = (const float*)d_in[3];
    const float* b1  = (const float*)d_in[4];
    const float* W2  = (const float*)d_in[5];
    const float* b2  = (const float*)d_in[6];
    const float* W3  = (const float*)d_in[7];
    const float* b3  = (const float*)d_in[8];

    const int  N = in_sizes[0] / H;     // 100000
    const long E = in_sizes[1];         // 1600000

    char* ws = (char*)d_ws;
    uint16_t* Bfrag = (uint16_t*)ws;                 // 32 KiB
    uint16_t* EFrag = (uint16_t*)(ws + 64 * 1024);   // 5 KiB
    uint16_t* pre   = (uint16_t*)(ws + 128 * 1024);  // N*128*2 = 25.6 MB (bf16)

    prep_weights<<<64, 256, 0, stream>>>(W1, W2, W3, Bfrag, EFrag);
    node_gemm<<<(N + 63) / 64, 256, 0, stream>>>(h, Bfrag, b1, pre, N);
    const int eblocks = (int)((E + 255) / 256);      // 4 waves x 64 edges per block
    edge_mlp<<<eblocks, 256, 0, stream>>>(pre, src, dst, EFrag, b2, b3,
                                          (float*)d_out, E);
}